// Round 18
// baseline (173.409 us; speedup 1.0000x reference)
//
#include <hip/hip_runtime.h>
#include <math.h>
#include <stdint.h>

#define N_PIX 4096
#define CDIM 256
#define DINNER 512

typedef float vf4 __attribute__((ext_vector_type(4)));
typedef float f32x4 __attribute__((ext_vector_type(4)));
typedef float f32x16 __attribute__((ext_vector_type(16)));
typedef _Float16 half8 __attribute__((ext_vector_type(8)));
typedef _Float16 half4v __attribute__((ext_vector_type(4)));
typedef __fp16 fp16x2 __attribute__((ext_vector_type(2)));
typedef uint32_t u32x2 __attribute__((ext_vector_type(2)));
typedef uint32_t u32x4 __attribute__((ext_vector_type(4)));

#define LOG2E 1.44269504f
#define C1 0.36067376f           /* 0.25 * log2e */
#define EXP2(x) __builtin_amdgcn_exp2f(x)

#define GLOAD_LDS16(g, l)                                                  \
    __builtin_amdgcn_global_load_lds(                                      \
        (const __attribute__((address_space(1))) unsigned int*)(g),       \
        (__attribute__((address_space(3))) unsigned int*)(l), 16, 0, 0)

// ---------------------------------------------------------------------------
// Kernel 1 (fused prep): rnorm+fmapT16 / Wg16 / Wout16   (unchanged)
// ---------------------------------------------------------------------------
__global__ __launch_bounds__(256) void prep_kernel(
    const float* __restrict__ fmap, float* __restrict__ rnorm,
    _Float16* __restrict__ fmapT16,
    const float* __restrict__ Wq, const float* __restrict__ Wv,
    const float* __restrict__ gamma, const float* __restrict__ Wout,
    _Float16* __restrict__ Wg16, _Float16* __restrict__ Wout16) {
    const int t = threadIdx.x;
    if (blockIdx.x < 128) {
        __shared__ float red[4][64];
        const int pl = t & 63;
        const int part = t >> 6;
        const int pix0 = blockIdx.x * 64;
        const int gp = pix0 + pl;
        const int b = gp >> 12, p = gp & 4095;
        const float* f = fmap + ((size_t)b * CDIM + part * 64) * N_PIX + p;
        _Float16* o16 = fmapT16 + (size_t)gp * CDIM + part * 64;
        float s = 0.f;
        #pragma unroll
        for (int c8 = 0; c8 < 64; c8 += 8) {
            half8 hv;
            #pragma unroll
            for (int e = 0; e < 8; ++e) {
                float x = f[(size_t)(c8 + e) * N_PIX];
                s = fmaf(x, x, s);
                hv[e] = (_Float16)x;
            }
            *(half8*)(o16 + c8) = hv;
        }
        red[part][pl] = s;
        __syncthreads();
        if (t < 64) {
            float tot = red[0][t] + red[1][t] + red[2][t] + red[3][t];
            rnorm[pix0 + t] = 16.0f / fmaxf(sqrtf(tot), 1e-12f);
        }
    } else if (blockIdx.x < 384) {
        const int o = (blockIdx.x - 128) * 4 + (t >> 6);
        const int c = (t & 63) * 4;
        const float* W = (o < DINNER) ? (Wq + (size_t)o * CDIM)
                                      : (Wv + (size_t)(o - DINNER) * CDIM);
        vf4 wv = *(const vf4*)(W + c);
        vf4 gv = *(const vf4*)(gamma + c);
        half4v h = {(_Float16)(wv[0] * gv[0]), (_Float16)(wv[1] * gv[1]),
                    (_Float16)(wv[2] * gv[2]), (_Float16)(wv[3] * gv[3])};
        *(half4v*)(Wg16 + (size_t)o * CDIM + c) = h;
    } else {
        const int idx = ((blockIdx.x - 384) * 256 + t) * 4;
        vf4 wv = *(const vf4*)(Wout + idx);
        half4v h = {(_Float16)wv[0], (_Float16)wv[1], (_Float16)wv[2], (_Float16)wv[3]};
        *(half4v*)(Wout16 + idx) = h;
    }
}

// ---------------------------------------------------------------------------
// Kernel 2: fp16 MFMA projection GEMM (unchanged from round 17).
//  Kst[bh][tile][d>>3][j][d&7], Vst[bh][tile][j>>3][d][j&7], cksq = -0.5*qsq.
// ---------------------------------------------------------------------------
__global__ __launch_bounds__(256) void proj_mfma(
    const _Float16* __restrict__ fmapT16,  // [b*4096+p][256]
    const _Float16* __restrict__ Wg16,     // [1024][256]
    const float* __restrict__ rnorm,       // [8192]
    _Float16* __restrict__ Kst, _Float16* __restrict__ Vst,
    float* __restrict__ cksq) {
    const int pt = blockIdx.x;             // 64
    const int mt = blockIdx.y;             // 16 (0..7 Q, 8..15 V)
    const int b = blockIdx.z;              // 2
    const int m0 = mt * 64;
    const bool isQ = (m0 < DINNER);
    const int h = (m0 & 511) >> 6;
    const int bh = b * 8 + h;
    const int p0 = pt * 64;

    const int t = threadIdx.x;
    const int w = t >> 6;
    const int lane = t & 63;
    const int col = lane & 15;
    const int g = lane >> 4;
    const int p = p0 + w * 16 + col;       // this lane's pixel
    const int j = w * 16 + col;            // pixel within the 64-tile

    const _Float16* bbase = fmapT16 + ((size_t)b * N_PIX + p) * CDIM;
    const _Float16* abase = Wg16 + (size_t)m0 * CDIM;

    f32x4 acc[4] = {};
    #pragma unroll
    for (int ks = 0; ks < 8; ++ks) {
        half8 bf = *(const half8*)(bbase + ks * 32 + g * 8);
        #pragma unroll
        for (int ms = 0; ms < 4; ++ms) {
            half8 af = *(const half8*)(abase + (size_t)(ms * 16 + col) * CDIM + ks * 32 + g * 8);
            acc[ms] = __builtin_amdgcn_mfma_f32_16x16x32_f16(af, bf, acc[ms], 0, 0, 0);
        }
    }

    const float rn = rnorm[b * N_PIX + p];
    _Float16 qh[4][4];
    #pragma unroll
    for (int ms = 0; ms < 4; ++ms)
        #pragma unroll
        for (int r = 0; r < 4; ++r)
            qh[ms][r] = (_Float16)(acc[ms][r] * rn);   // (d = ms*16+4g+r, pixel j)

    if (isQ) {
        float qs = 0.f;
        #pragma unroll
        for (int ms = 0; ms < 4; ++ms)
            #pragma unroll
            for (int r = 0; r < 4; ++r) {
                float qv = (float)qh[ms][r];
                qs = fmaf(qv, qv, qs);
            }
        qs += __shfl_xor(qs, 16);
        qs += __shfl_xor(qs, 32);
        _Float16* kt2 = Kst + ((size_t)bh * 64 + pt) * 4096;
        #pragma unroll
        for (int ms = 0; ms < 4; ++ms) {
            half4v hv = {qh[ms][0], qh[ms][1], qh[ms][2], qh[ms][3]};
            *(half4v*)(kt2 + (ms * 2 + (g >> 1)) * 512 + j * 8 + (g & 1) * 4) = hv;
        }
        if (g == 0)
            cksq[(size_t)bh * N_PIX + p] = -0.5f * qs;
    } else {
        _Float16* vt2 = Vst + ((size_t)bh * 64 + pt) * 4096;
        const int gj = j >> 3, je = j & 7;
        #pragma unroll
        for (int ms = 0; ms < 4; ++ms)
            #pragma unroll
            for (int r = 0; r < 4; ++r) {
                const int d = ms * 16 + 4 * g + r;
                vt2[gj * 512 + d * 8 + je] = qh[ms][r];
            }
    }
}

// ---------------------------------------------------------------------------
// Kernel 3: 32x32x16 MFMA flash attention, swapped QK^T — round-16 schedule:
// 2 tiles per barrier, software-pipelined QKT_A/sm_A/QKT_B/PV_A/sm_B/PV_B.
// 8 waves: rg = w&3 (32 q-rows), jh = w>>2 (32-j half).  Epilogue scratch
// aliases kv_lds (dead after final barrier) to keep LDS at 64 KB.
// ---------------------------------------------------------------------------
__global__ __launch_bounds__(512, 4) void attn_kernel(
    const _Float16* __restrict__ Kst,  // [bh][tile][d>>3][j][d&7]
    const _Float16* __restrict__ Vst,  // [bh][tile][j>>3][d][j&7]
    const float* __restrict__ cksq,    // [bh][p] = -0.5*ksq
    const float* __restrict__ nullkv,  // [2][8][64] fp32
    _Float16* __restrict__ AO16)       // [b*4096+p][512]
{
    const int n = blockIdx.x;
    const int slot = n >> 3;
    const int bh = (n & 7) * 2 + (slot >> 5);   // XCD swizzle
    const int it = slot & 31;
    const int h = bh & 7;

    __shared__ __align__(16) _Float16 kv_lds[2][4][4096];  // [buf][KA,KB,VA,VB]
    float* led = (float*)&kv_lds[0][0][0];  // epilogue alias (35 KB < 64 KB)

    const int t = threadIdx.x;
    const int w = t >> 6;          // 0..7
    const int lane = t & 63;
    const int qcol = lane & 31;
    const int hi = lane >> 5;
    const int rg = w & 3, jh = w >> 2;

    const _Float16* kbase = Kst + (size_t)bh * (64 * 4096);
    const _Float16* vbase = Vst + (size_t)bh * (64 * 4096);
    const float* ck = cksq + (size_t)bh * N_PIX;
    const int i0 = it * 128 + rg * 32;
    const int qi = i0 + qcol;

    // prologue: stage tiles 0,1 into buf 0
    GLOAD_LDS16(kbase + w * 512 + lane * 8, &kv_lds[0][0][w * 512]);
    GLOAD_LDS16(kbase + 4096 + w * 512 + lane * 8, &kv_lds[0][1][w * 512]);
    GLOAD_LDS16(vbase + w * 512 + lane * 8, &kv_lds[0][2][w * 512]);
    GLOAD_LDS16(vbase + 4096 + w * 512 + lane * 8, &kv_lds[0][3][w * 512]);

    // Q fragments (B-operand): k-map d = dk*16 + hi*8 + e
    half8 qf[4];
    #pragma unroll
    for (int dk = 0; dk < 4; ++dk)
        qf[dk] = *(const half8*)(kbase + (size_t)(qi >> 6) * 4096 +
                                 (dk * 2 + hi) * 512 + (qi & 63) * 8);

    // null kv: per-lane partial over its 32 d, combined across hi
    float nd = 0.f, nkk = 0.f;
    #pragma unroll
    for (int dk = 0; dk < 4; ++dk) {
        const float* np = nullkv + h * 64 + dk * 16 + hi * 8;
        #pragma unroll
        for (int e = 0; e < 8; ++e) {
            float nkval = np[e];
            nkk = fmaf(nkval, nkval, nkk);
            nd = fmaf((float)qf[dk][e], nkval, nd);
        }
    }
    nd += __shfl_xor(nd, 32);
    nkk += __shfl_xor(nkk, 32);

    float m_, l_;
    f32x16 oacc[2];
    {
        float nsim = fmaf(0.25f, nd, -0.125f * nkk) * LOG2E;
        float ci = -C1 * ck[qi];
        m_ = fmaxf(ci, nsim);
        if (jh == 0) {
            float wn = EXP2(nsim - m_);
            l_ = 0.5f * wn;                 // summed over hi pair later
            #pragma unroll
            for (int dh = 0; dh < 2; ++dh)
                #pragma unroll
                for (int q = 0; q < 4; ++q) {
                    vf4 nv = *(const vf4*)(nullkv + DINNER + h * 64 + dh * 32 + q * 8 + hi * 4);
                    #pragma unroll
                    for (int rr = 0; rr < 4; ++rr)
                        oacc[dh][q * 4 + rr] = wn * nv[rr];
                }
        } else {
            l_ = 0.f;
            #pragma unroll
            for (int dh = 0; dh < 2; ++dh)
                #pragma unroll
                for (int rr = 0; rr < 16; ++rr)
                    oacc[dh][rr] = 0.f;
        }
    }
    const float nm = -m_;

    // phase helpers -------------------------------------------------------
    auto qkt = [&](const _Float16* kl, int j0g, f32x16& sf) {
        #pragma unroll
        for (int q = 0; q < 4; ++q) {
            vf4 c4 = *(const vf4*)&ck[j0g + q * 8 + hi * 4];
            #pragma unroll
            for (int rr = 0; rr < 4; ++rr)
                sf[q * 4 + rr] = c4[rr];
        }
        __builtin_amdgcn_s_setprio(1);
        #pragma unroll
        for (int dk = 0; dk < 4; ++dk) {
            half8 kf = *(const half8*)(kl + (dk * 2 + hi) * 512 + (jh * 32 + qcol) * 8);
            sf = __builtin_amdgcn_mfma_f32_32x32x16_f16(kf, qf[dk], sf, 0, 0, 0);
        }
        __builtin_amdgcn_s_setprio(0);
    };
    auto sm = [&](const f32x16& sf, half8 (&pf)[2]) {
        float ex[16];
        float ls = 0.f;
        #pragma unroll
        for (int rr = 0; rr < 16; ++rr) {
            ex[rr] = EXP2(fmaf(C1, sf[rr], nm));
            ls += ex[rr];
        }
        l_ += ls;
        #pragma unroll
        for (int c = 0; c < 2; ++c) {
            uint32_t a0 = __builtin_bit_cast(uint32_t, __builtin_amdgcn_cvt_pkrtz(ex[8 * c + 0], ex[8 * c + 1]));
            uint32_t a1 = __builtin_bit_cast(uint32_t, __builtin_amdgcn_cvt_pkrtz(ex[8 * c + 2], ex[8 * c + 3]));
            uint32_t b0 = __builtin_bit_cast(uint32_t, __builtin_amdgcn_cvt_pkrtz(ex[8 * c + 4], ex[8 * c + 5]));
            uint32_t b1 = __builtin_bit_cast(uint32_t, __builtin_amdgcn_cvt_pkrtz(ex[8 * c + 6], ex[8 * c + 7]));
            u32x2 s0 = __builtin_amdgcn_permlane32_swap(a0, b0, false, false);
            u32x2 s1 = __builtin_amdgcn_permlane32_swap(a1, b1, false, false);
            pf[c] = __builtin_bit_cast(half8, (u32x4){s0[0], s1[0], s0[1], s1[1]});
        }
    };
    auto pv = [&](const _Float16* vl, const half8 (&pf)[2]) {
        __builtin_amdgcn_s_setprio(1);
        #pragma unroll
        for (int c = 0; c < 2; ++c)
            #pragma unroll
            for (int dh = 0; dh < 2; ++dh) {
                half8 vfrg = *(const half8*)(vl + (jh * 4 + c * 2 + hi) * 512 +
                                             (dh * 32 + qcol) * 8);
                oacc[dh] = __builtin_amdgcn_mfma_f32_32x32x16_f16(vfrg, pf[c], oacc[dh], 0, 0, 0);
            }
        __builtin_amdgcn_s_setprio(0);
    };

    __syncthreads();   // tiles 0,1 staged

    int cb = 0;
    #pragma unroll 1
    for (int jp = 0; jp < 32; ++jp) {
        if (jp < 31) {
            const _Float16* kt = kbase + (size_t)(jp * 2 + 2) * 4096;
            const _Float16* vt = vbase + (size_t)(jp * 2 + 2) * 4096;
            _Float16* dst = &kv_lds[cb ^ 1][0][0];
            GLOAD_LDS16(kt + w * 512 + lane * 8, dst + w * 512);
            GLOAD_LDS16(kt + 4096 + w * 512 + lane * 8, dst + 4096 + w * 512);
            GLOAD_LDS16(vt + w * 512 + lane * 8, dst + 8192 + w * 512);
            GLOAD_LDS16(vt + 4096 + w * 512 + lane * 8, dst + 12288 + w * 512);
        }
        const _Float16* klA = &kv_lds[cb][0][0];
        const _Float16* klB = &kv_lds[cb][1][0];
        const _Float16* vlA = &kv_lds[cb][2][0];
        const _Float16* vlB = &kv_lds[cb][3][0];
        const int j0A = jp * 128 + jh * 32;
        const int j0B = jp * 128 + 64 + jh * 32;

        f32x16 sfA, sfB;
        half8 pfA[2], pfB[2];
        qkt(klA, j0A, sfA);      // MFMA
        sm(sfA, pfA);            // trans/VALU (drains async)
        qkt(klB, j0B, sfB);      // MFMA fills while sm_A drains
        pv(vlA, pfA);            // pf_A ready
        sm(sfB, pfB);            // trans/VALU
        pv(vlB, pfB);            // MFMA
        __syncthreads();
        cb ^= 1;
    }

    // combine hi-pair l, then jh pair via aliased LDS, normalize, store
    l_ += __shfl_xor(l_, 32);
    if (jh == 1) {
        float* lp = led + ((size_t)rg * 64 + lane) * 34;
        #pragma unroll
        for (int dh = 0; dh < 2; ++dh)
            #pragma unroll
            for (int rr = 0; rr < 16; ++rr)
                lp[dh * 16 + rr] = oacc[dh][rr];
        lp[32] = l_;
    }
    __syncthreads();
    if (jh == 0) {
        const float* lp = led + ((size_t)rg * 64 + lane) * 34;
        l_ += lp[32];
        float linv = 1.f / l_;
        _Float16* aop = AO16 + ((size_t)(bh >> 3) * N_PIX + qi) * DINNER + (h << 6);
        #pragma unroll
        for (int dh = 0; dh < 2; ++dh)
            #pragma unroll
            for (int q = 0; q < 4; ++q) {
                half4v hv;
                #pragma unroll
                for (int rr = 0; rr < 4; ++rr) {
                    float v = oacc[dh][q * 4 + rr] + lp[dh * 16 + q * 4 + rr];
                    hv[rr] = (_Float16)(v * linv);
                }
                *(half4v*)(aop + dh * 32 + q * 8 + hi * 4) = hv;
            }
    }
}

// ---------------------------------------------------------------------------
// Kernel 4: fp16 MFMA output GEMM, split-K (unchanged)
// ---------------------------------------------------------------------------
__global__ __launch_bounds__(512) void outproj_mfma(
    const _Float16* __restrict__ AO16,    // [b*4096+p][512]
    const _Float16* __restrict__ Wout16,  // [256][512]
    float* __restrict__ out) {
    const int pt = blockIdx.x;   // 64
    const int mt = blockIdx.y;   // 4
    const int b = blockIdx.z;    // 2
    const int t = threadIdx.x;
    const int w = t >> 6, lane = t & 63, col = lane & 15, g = lane >> 4;
    const int wp = w & 3, wk = w >> 2;
    const int p = pt * 64 + wp * 16 + col;

    __shared__ f32x4 red[4][4][64];

    const _Float16* bbase = AO16 + ((size_t)b * N_PIX + p) * DINNER + wk * 256;
    const _Float16* abase = Wout16 + (size_t)(mt * 64) * DINNER + wk * 256;

    f32x4 acc[4] = {};
    #pragma unroll
    for (int ks = 0; ks < 8; ++ks) {
        half8 bf = *(const half8*)(bbase + ks * 32 + g * 8);
        #pragma unroll
        for (int ms = 0; ms < 4; ++ms) {
            half8 af = *(const half8*)(abase + (size_t)(ms * 16 + col) * DINNER + ks * 32 + g * 8);
            acc[ms] = __builtin_amdgcn_mfma_f32_16x16x32_f16(af, bf, acc[ms], 0, 0, 0);
        }
    }

    if (wk == 1) {
        #pragma unroll
        for (int ms = 0; ms < 4; ++ms)
            red[wp][ms][lane] = acc[ms];
    }
    __syncthreads();
    if (wk == 0) {
        float* ob = out + ((size_t)b * CDIM + mt * 64) * N_PIX + p;
        #pragma unroll
        for (int ms = 0; ms < 4; ++ms) {
            f32x4 s = acc[ms] + red[wp][ms][lane];
            #pragma unroll
            for (int r = 0; r < 4; ++r)
                ob[(size_t)(ms * 16 + 4 * g + r) * N_PIX] = s[r];
        }
    }
}

// ---------------------------------------------------------------------------
extern "C" void kernel_launch(void* const* d_in, const int* in_sizes, int n_in,
                              void* d_out, int out_size, void* d_ws, size_t ws_size,
                              hipStream_t stream) {
    const float* fmap   = (const float*)d_in[0];
    const float* gamma  = (const float*)d_in[1];
    const float* Wq     = (const float*)d_in[2];
    const float* Wv     = (const float*)d_in[3];
    const float* Wout   = (const float*)d_in[4];
    const float* nullkv = (const float*)d_in[5];
    float* out = (float*)d_out;

    char* wsb = (char*)d_ws;
    _Float16* Kst = (_Float16*)wsb;                          // 8 MB
    _Float16* Vst = (_Float16*)(wsb + (8u << 20));           // 8 MB
    _Float16* fmapT16 = (_Float16*)(wsb + (16u << 20));      // 4 MB (dead before AO16)
    _Float16* Wg16    = (_Float16*)(wsb + (20u << 20));      // 512 KB
    _Float16* AO16    = (_Float16*)(wsb + (16u << 20));      // 8 MB
    _Float16* Wout16  = (_Float16*)(wsb + (31u << 20));      // 256 KB
    float*    cksq    = (float*)(wsb + (32u << 20));         // 256 KB
    float*    rnorm   = (float*)(wsb + (33u << 20));         // 32 KB

    prep_kernel<<<512, 256, 0, stream>>>(fmap, rnorm, fmapT16,
                                         Wq, Wv, gamma, Wout, Wg16, Wout16);
    proj_mfma<<<dim3(64, 16, 2), 256, 0, stream>>>(fmapT16, Wg16, rnorm, Kst, Vst, cksq);
    attn_kernel<<<512, 512, 0, stream>>>(Kst, Vst, cksq, nullkv, AO16);
    outproj_mfma<<<dim3(64, 4, 2), 512, 0, stream>>>(AO16, Wout16, out);
}

// Round 19
// 159.623 us; speedup vs baseline: 1.0864x; 1.0864x over previous
//
#include <hip/hip_runtime.h>
#include <math.h>
#include <stdint.h>

#define N_PIX 4096
#define CDIM 256
#define DINNER 512

typedef float vf4 __attribute__((ext_vector_type(4)));
typedef float f32x4 __attribute__((ext_vector_type(4)));
typedef _Float16 half8 __attribute__((ext_vector_type(8)));
typedef _Float16 half4v __attribute__((ext_vector_type(4)));
typedef __fp16 fp16x2 __attribute__((ext_vector_type(2)));
typedef uint32_t u32x4 __attribute__((ext_vector_type(4)));

// log2(e) scalings: softmax done in exp2 domain
#define LOG2E 1.44269504f
#define C1 0.36067376f           /* 0.25 * log2e */
// cksq stores -0.5*qsq; log2-domain diag max ci = -C1 * cksq

#define EXP2(x) __builtin_amdgcn_exp2f(x)   /* raw v_exp_f32, ~1 ulp, FTZ ok */

// async global->LDS, 16B per lane, LDS dest = wave-uniform base + lane*16
#define GLOAD_LDS16(g, l)                                                  \
    __builtin_amdgcn_global_load_lds(                                      \
        (const __attribute__((address_space(1))) unsigned int*)(g),       \
        (__attribute__((address_space(3))) unsigned int*)(l), 16, 0, 0)

// ---------------------------------------------------------------------------
// Kernel 1 (fused prep):
//  blocks   0..127: rnorm + fp16 transpose of fmap
//  blocks 128..383: Wg16[o][c] = fp16(W[o][c]*gamma[c])
//  blocks 384..511: Wout16 = fp16(Wout)
// ---------------------------------------------------------------------------
__global__ __launch_bounds__(256) void prep_kernel(
    const float* __restrict__ fmap, float* __restrict__ rnorm,
    _Float16* __restrict__ fmapT16,
    const float* __restrict__ Wq, const float* __restrict__ Wv,
    const float* __restrict__ gamma, const float* __restrict__ Wout,
    _Float16* __restrict__ Wg16, _Float16* __restrict__ Wout16) {
    const int t = threadIdx.x;
    if (blockIdx.x < 128) {
        __shared__ float red[4][64];
        const int pl = t & 63;
        const int part = t >> 6;
        const int pix0 = blockIdx.x * 64;
        const int gp = pix0 + pl;
        const int b = gp >> 12, p = gp & 4095;
        const float* f = fmap + ((size_t)b * CDIM + part * 64) * N_PIX + p;
        _Float16* o16 = fmapT16 + (size_t)gp * CDIM + part * 64;
        float s = 0.f;
        #pragma unroll
        for (int c8 = 0; c8 < 64; c8 += 8) {
            half8 hv;
            #pragma unroll
            for (int e = 0; e < 8; ++e) {
                float x = f[(size_t)(c8 + e) * N_PIX];
                s = fmaf(x, x, s);
                hv[e] = (_Float16)x;
            }
            *(half8*)(o16 + c8) = hv;
        }
        red[part][pl] = s;
        __syncthreads();
        if (t < 64) {
            float tot = red[0][t] + red[1][t] + red[2][t] + red[3][t];
            rnorm[pix0 + t] = 16.0f / fmaxf(sqrtf(tot), 1e-12f);
        }
    } else if (blockIdx.x < 384) {
        const int o = (blockIdx.x - 128) * 4 + (t >> 6);
        const int c = (t & 63) * 4;
        const float* W = (o < DINNER) ? (Wq + (size_t)o * CDIM)
                                      : (Wv + (size_t)(o - DINNER) * CDIM);
        vf4 wv = *(const vf4*)(W + c);
        vf4 gv = *(const vf4*)(gamma + c);
        half4v h = {(_Float16)(wv[0] * gv[0]), (_Float16)(wv[1] * gv[1]),
                    (_Float16)(wv[2] * gv[2]), (_Float16)(wv[3] * gv[3])};
        *(half4v*)(Wg16 + (size_t)o * CDIM + c) = h;
    } else {
        const int idx = ((blockIdx.x - 384) * 256 + t) * 4;
        vf4 wv = *(const vf4*)(Wout + idx);
        half4v h = {(_Float16)wv[0], (_Float16)wv[1], (_Float16)wv[2], (_Float16)wv[3]};
        *(half4v*)(Wout16 + idx) = h;
    }
}

// ---------------------------------------------------------------------------
// Kernel 2: fp16 MFMA projection GEMM.  cksq stores -0.5*qsq.
//  Kst[bh][tile][j][slot][8]: element (j, d) at j*64 + ((d>>3) ^ (j&7))*8 + (d&7)
//  Vst[bh][tile][d][slot][8]: slot (d, sv) at sv ^ (d&7), j-permuted per 64.
// ---------------------------------------------------------------------------
__global__ __launch_bounds__(256) void proj_mfma(
    const _Float16* __restrict__ fmapT16,  // [b*4096+p][256]
    const _Float16* __restrict__ Wg16,     // [1024][256]
    const float* __restrict__ rnorm,       // [8192]
    _Float16* __restrict__ Kst, _Float16* __restrict__ Vst,
    float* __restrict__ cksq) {
    const int pt = blockIdx.x;             // 64
    const int mt = blockIdx.y;             // 16 (0..7 Q, 8..15 V)
    const int b = blockIdx.z;              // 2
    const int m0 = mt * 64;
    const bool isQ = (m0 < DINNER);
    const int h = (m0 & 511) >> 6;
    const int bh = b * 8 + h;
    const int p0 = pt * 64;

    const int t = threadIdx.x;
    const int w = t >> 6;
    const int lane = t & 63;
    const int col = lane & 15;
    const int g = lane >> 4;
    const int p = p0 + w * 16 + col;       // this lane's pixel
    const int j = w * 16 + col;            // pixel within the 64-tile

    const _Float16* bbase = fmapT16 + ((size_t)b * N_PIX + p) * CDIM;
    const _Float16* abase = Wg16 + (size_t)m0 * CDIM;

    f32x4 acc[4] = {};
    #pragma unroll
    for (int ks = 0; ks < 8; ++ks) {
        half8 bf = *(const half8*)(bbase + ks * 32 + g * 8);
        #pragma unroll
        for (int ms = 0; ms < 4; ++ms) {
            half8 af = *(const half8*)(abase + (size_t)(ms * 16 + col) * CDIM + ks * 32 + g * 8);
            acc[ms] = __builtin_amdgcn_mfma_f32_16x16x32_f16(af, bf, acc[ms], 0, 0, 0);
        }
    }

    const float rn = rnorm[b * N_PIX + p];
    _Float16 qh[4][4];
    #pragma unroll
    for (int ms = 0; ms < 4; ++ms)
        #pragma unroll
        for (int r = 0; r < 4; ++r)
            qh[ms][r] = (_Float16)(acc[ms][r] * rn);

    if (isQ) {
        float qs = 0.f;
        #pragma unroll
        for (int ms = 0; ms < 4; ++ms)
            #pragma unroll
            for (int r = 0; r < 4; ++r) {
                float qv = (float)qh[ms][r];
                qs = fmaf(qv, qv, qs);
            }
        qs += __shfl_xor(qs, 16);
        qs += __shfl_xor(qs, 32);
        _Float16* kt2 = Kst + ((size_t)bh * 64 + pt) * 4096;
        #pragma unroll
        for (int ms = 0; ms < 4; ++ms) {
            half4v hv = {qh[ms][0], qh[ms][1], qh[ms][2], qh[ms][3]};
            *(half4v*)(kt2 + j * 64 + (((ms * 2 + (g >> 1)) ^ (j & 7)) * 8) + (g & 1) * 4) = hv;
        }
        if (g == 0)
            cksq[(size_t)bh * N_PIX + p] = -0.5f * qs;
    } else {
        _Float16* vt2 = Vst + ((size_t)bh * 64 + pt) * 4096;
        const int svb = ((j >> 5) << 2) + ((j >> 2) & 3);
        const int off = ((j >> 4) & 1) * 4 + (j & 3);
        #pragma unroll
        for (int ms = 0; ms < 4; ++ms)
            #pragma unroll
            for (int r = 0; r < 4; ++r) {
                const int d = ms * 16 + 4 * g + r;
                vt2[d * 64 + ((svb ^ (d & 7)) << 3) + off] = qh[ms][r];
            }
    }
}

// ---------------------------------------------------------------------------
// Kernel 3: fp16 MFMA flash attention, swapped QK^T, 8 waves x 16 q-rows,
// 2 KV tiles per barrier, fused 64KB LDS.  Software-pipelined 2-tile body:
// QKT_A -> exp_A -> QKT_B -> PV_A -> exp_B -> PV_B.
// S^T accumulator init = -0.5*ksq read from L2; exponent via raw v_exp_f32.
// ---------------------------------------------------------------------------
__global__ __launch_bounds__(512, 4) void attn_kernel(
    const _Float16* __restrict__ Kst,  // [bh][64][4096] xor-slotted
    const _Float16* __restrict__ Vst,  // [bh][64][4096] xor-slotted
    const float* __restrict__ cksq,    // [bh][p] = -0.5*ksq
    const float* __restrict__ nullkv,  // [2][8][64] fp32
    _Float16* __restrict__ AO16)       // [b*4096+p][512]
{
    const int n = blockIdx.x;
    const int slot = n >> 3;
    const int bh = (n & 7) * 2 + (slot >> 5);   // XCD swizzle: 2 bh per XCD
    const int it = slot & 31;
    const int h = bh & 7;

    // [buf][K(t0),K(t1),V(t0),V(t1)][4096]
    __shared__ __align__(16) _Float16 kv_lds[2][4][4096];

    const int t = threadIdx.x;
    const int w = t >> 6;          // 0..7
    const int lane = t & 63;
    const int col = lane & 15;
    const int g = lane >> 4;
    const int c7 = col & 7;

    const _Float16* kbase = Kst + (size_t)bh * (64 * 4096);
    const _Float16* vbase = Vst + (size_t)bh * (64 * 4096);
    const float* ck = cksq + (size_t)bh * N_PIX;
    const int i0 = it * 128 + w * 16;

    // prologue: stage tiles 0,1 into buf 0 (wave w stages chunk w of each)
    GLOAD_LDS16(kbase + w * 512 + lane * 8, &kv_lds[0][0][w * 512]);
    GLOAD_LDS16(kbase + 4096 + w * 512 + lane * 8, &kv_lds[0][1][w * 512]);
    GLOAD_LDS16(vbase + w * 512 + lane * 8, &kv_lds[0][2][w * 512]);
    GLOAD_LDS16(vbase + 4096 + w * 512 + lane * 8, &kv_lds[0][3][w * 512]);

    // Q fragment (B-operand of S^T mfma) from global Kst: d = dk*32+g*8+e
    half8 qf[2];
    {
        const int i = i0 + col;
        #pragma unroll
        for (int dk = 0; dk < 2; ++dk)
            qf[dk] = *(const half8*)(kbase + (size_t)(i >> 6) * 4096 +
                                     (i & 63) * 64 + ((dk * 4 + g) ^ c7) * 8);
    }

    // null kv: per-lane nd for q-row = l&15 after g-group reduction
    float nd = 0.f, nkk = 0.f;
    #pragma unroll
    for (int dk = 0; dk < 2; ++dk) {
        const float* np = nullkv + h * 64 + dk * 32 + g * 8;
        #pragma unroll
        for (int e = 0; e < 8; ++e) {
            float nkval = np[e];
            nkk = fmaf(nkval, nkval, nkk);
            nd = fmaf((float)qf[dk][e], nkval, nd);
        }
    }
    nd += __shfl_xor(nd, 16); nd += __shfl_xor(nd, 32);
    nkk += __shfl_xor(nkk, 16); nkk += __shfl_xor(nkk, 32);

    // null V values at d = dt*16 + 4g + r (matches O^T D-layout)
    vf4 nv4[4];
    #pragma unroll
    for (int dt = 0; dt < 4; ++dt)
        nv4[dt] = *(const vf4*)(nullkv + DINNER + h * 64 + dt * 16 + 4 * g);

    float m_;
    f32x4 oaccT[4];
    f32x4 lacc;
    {
        float nsim = fmaf(0.25f, nd, -0.125f * nkk) * LOG2E;
        float ci = -C1 * ck[i0 + col];        // log2-domain diag max
        m_ = fmaxf(ci, nsim);
        float wn = EXP2(nsim - m_);
        lacc = f32x4{wn, wn, wn, wn};
        #pragma unroll
        for (int dt = 0; dt < 4; ++dt)
            #pragma unroll
            for (int r = 0; r < 4; ++r)
                oaccT[dt][r] = wn * nv4[dt][r];
    }

    const half8 ones1 = {(_Float16)1.f, (_Float16)1.f, (_Float16)1.f, (_Float16)1.f,
                         (_Float16)1.f, (_Float16)1.f, (_Float16)1.f, (_Float16)1.f};
    const float nm = -m_;

    // phase helpers -------------------------------------------------------
    auto qkt = [&](const _Float16* kl, int j0, f32x4 (&sfT)[4]) {
        #pragma unroll
        for (int jt = 0; jt < 4; ++jt)
            sfT[jt] = *(const f32x4*)&ck[j0 + jt * 16 + 4 * g];
        half8 kf[4][2];
        #pragma unroll
        for (int jt = 0; jt < 4; ++jt)
            #pragma unroll
            for (int dk = 0; dk < 2; ++dk)
                kf[jt][dk] = *(const half8*)(kl + (jt * 16 + col) * 64 +
                                             ((dk * 4 + g) ^ c7) * 8);
        __builtin_amdgcn_s_setprio(1);
        #pragma unroll
        for (int jt = 0; jt < 4; ++jt) {
            sfT[jt] = __builtin_amdgcn_mfma_f32_16x16x32_f16(kf[jt][0], qf[0], sfT[jt], 0, 0, 0);
            sfT[jt] = __builtin_amdgcn_mfma_f32_16x16x32_f16(kf[jt][1], qf[1], sfT[jt], 0, 0, 0);
        }
        __builtin_amdgcn_s_setprio(0);
    };
    auto softmax = [&](const f32x4 (&sfT)[4], half8& pf0, half8& pf1) {
        uint32_t us[8];
        #pragma unroll
        for (int jt = 0; jt < 4; ++jt) {
            float a0 = EXP2(fmaf(C1, sfT[jt][0], nm));
            float a1 = EXP2(fmaf(C1, sfT[jt][1], nm));
            float a2 = EXP2(fmaf(C1, sfT[jt][2], nm));
            float a3 = EXP2(fmaf(C1, sfT[jt][3], nm));
            us[jt * 2]     = __builtin_bit_cast(uint32_t, __builtin_amdgcn_cvt_pkrtz(a0, a1));
            us[jt * 2 + 1] = __builtin_bit_cast(uint32_t, __builtin_amdgcn_cvt_pkrtz(a2, a3));
        }
        pf0 = __builtin_bit_cast(half8, (u32x4){us[0], us[1], us[2], us[3]});
        pf1 = __builtin_bit_cast(half8, (u32x4){us[4], us[5], us[6], us[7]});
    };
    auto pv = [&](const _Float16* vl, half8 pf0, half8 pf1) {
        __builtin_amdgcn_s_setprio(1);
        #pragma unroll
        for (int dt = 0; dt < 4; ++dt) {
            half8 v0 = *(const half8*)(vl + (dt * 16 + col) * 64 + ((0 * 4 + g) ^ c7) * 8);
            half8 v1 = *(const half8*)(vl + (dt * 16 + col) * 64 + ((1 * 4 + g) ^ c7) * 8);
            oaccT[dt] = __builtin_amdgcn_mfma_f32_16x16x32_f16(v0, pf0, oaccT[dt], 0, 0, 0);
            oaccT[dt] = __builtin_amdgcn_mfma_f32_16x16x32_f16(v1, pf1, oaccT[dt], 0, 0, 0);
        }
        lacc = __builtin_amdgcn_mfma_f32_16x16x32_f16(ones1, pf0, lacc, 0, 0, 0);
        lacc = __builtin_amdgcn_mfma_f32_16x16x32_f16(ones1, pf1, lacc, 0, 0, 0);
        __builtin_amdgcn_s_setprio(0);
    };

    __syncthreads();   // tiles 0,1 staged

    int cb = 0;
    #pragma unroll 1
    for (int jp = 0; jp < 32; ++jp) {
        if (jp < 31) {
            const _Float16* kt = kbase + (size_t)(jp * 2 + 2) * 4096;
            const _Float16* vt = vbase + (size_t)(jp * 2 + 2) * 4096;
            _Float16* dst = &kv_lds[cb ^ 1][0][0];
            GLOAD_LDS16(kt + w * 512 + lane * 8, dst + w * 512);
            GLOAD_LDS16(kt + 4096 + w * 512 + lane * 8, dst + 4096 + w * 512);
            GLOAD_LDS16(vt + w * 512 + lane * 8, dst + 8192 + w * 512);
            GLOAD_LDS16(vt + 4096 + w * 512 + lane * 8, dst + 12288 + w * 512);
        }
        const int j0 = jp * 128;
        const _Float16* klA = &kv_lds[cb][0][0];
        const _Float16* klB = &kv_lds[cb][1][0];
        const _Float16* vlA = &kv_lds[cb][2][0];
        const _Float16* vlB = &kv_lds[cb][3][0];

        // software-pipelined 2-tile schedule
        f32x4 sfTA[4], sfTB[4];
        half8 pfA0, pfA1, pfB0, pfB1;
        qkt(klA, j0, sfTA);            // MFMA
        softmax(sfTA, pfA0, pfA1);     // trans (issues, pipe drains async)
        qkt(klB, j0 + 64, sfTB);       // MFMA fills while exp_A drains
        pv(vlA, pfA0, pfA1);           // pf_A ready by now
        softmax(sfTB, pfB0, pfB1);     // trans
        pv(vlB, pfB0, pfB1);           // MFMA
        __syncthreads();   // staging complete; reads of this buf done
        cb ^= 1;
    }

    // epilogue: l complete per lane, normalize, store fp16 AO16[p][c]
    {
        float linv = 1.f / lacc[0];
        const f32x4 lv = {linv, linv, linv, linv};
        const int p = i0 + col;
        _Float16* aop = AO16 + ((size_t)(bh >> 3) * N_PIX + p) * DINNER + (h << 6);
        #pragma unroll
        for (int dt = 0; dt < 4; ++dt) {
            f32x4 ov = oaccT[dt] * lv;
            half4v hv = {(_Float16)ov[0], (_Float16)ov[1],
                         (_Float16)ov[2], (_Float16)ov[3]};
            *(half4v*)(aop + dt * 16 + 4 * g) = hv;
        }
    }
}

// ---------------------------------------------------------------------------
// Kernel 4: fp16 MFMA output GEMM, split-K: 8 waves (512 thr), wave (wp, wk)
// computes 64m x 16p over K-half wk; pair (wk=0, wk=1) combines via LDS.
// ---------------------------------------------------------------------------
__global__ __launch_bounds__(512) void outproj_mfma(
    const _Float16* __restrict__ AO16,    // [b*4096+p][512]
    const _Float16* __restrict__ Wout16,  // [256][512]
    float* __restrict__ out) {
    const int pt = blockIdx.x;   // 64
    const int mt = blockIdx.y;   // 4
    const int b = blockIdx.z;    // 2
    const int t = threadIdx.x;
    const int w = t >> 6, lane = t & 63, col = lane & 15, g = lane >> 4;
    const int wp = w & 3, wk = w >> 2;
    const int p = pt * 64 + wp * 16 + col;

    __shared__ f32x4 red[4][4][64];   // [wp][ms][lane], 16 KB

    const _Float16* bbase = AO16 + ((size_t)b * N_PIX + p) * DINNER + wk * 256;
    const _Float16* abase = Wout16 + (size_t)(mt * 64) * DINNER + wk * 256;

    f32x4 acc[4] = {};
    #pragma unroll
    for (int ks = 0; ks < 8; ++ks) {
        half8 bf = *(const half8*)(bbase + ks * 32 + g * 8);
        #pragma unroll
        for (int ms = 0; ms < 4; ++ms) {
            half8 af = *(const half8*)(abase + (size_t)(ms * 16 + col) * DINNER + ks * 32 + g * 8);
            acc[ms] = __builtin_amdgcn_mfma_f32_16x16x32_f16(af, bf, acc[ms], 0, 0, 0);
        }
    }

    if (wk == 1) {
        #pragma unroll
        for (int ms = 0; ms < 4; ++ms)
            red[wp][ms][lane] = acc[ms];
    }
    __syncthreads();
    if (wk == 0) {
        float* ob = out + ((size_t)b * CDIM + mt * 64) * N_PIX + p;
        #pragma unroll
        for (int ms = 0; ms < 4; ++ms) {
            f32x4 s = acc[ms] + red[wp][ms][lane];
            #pragma unroll
            for (int r = 0; r < 4; ++r)
                ob[(size_t)(ms * 16 + 4 * g + r) * N_PIX] = s[r];
        }
    }
}

// ---------------------------------------------------------------------------
extern "C" void kernel_launch(void* const* d_in, const int* in_sizes, int n_in,
                              void* d_out, int out_size, void* d_ws, size_t ws_size,
                              hipStream_t stream) {
    const float* fmap   = (const float*)d_in[0];
    const float* gamma  = (const float*)d_in[1];
    const float* Wq     = (const float*)d_in[2];
    const float* Wv     = (const float*)d_in[3];
    const float* Wout   = (const float*)d_in[4];
    const float* nullkv = (const float*)d_in[5];
    float* out = (float*)d_out;

    char* wsb = (char*)d_ws;
    _Float16* Kst = (_Float16*)wsb;                          // 8 MB
    _Float16* Vst = (_Float16*)(wsb + (8u << 20));           // 8 MB
    // fmapT16 (4 MB) + Wg16 (0.5 MB) overlay the AO16 region: both are dead
    // before attn_kernel writes AO16 (+16MB..+24MB).
    _Float16* fmapT16 = (_Float16*)(wsb + (16u << 20));      // 4 MB
    _Float16* Wg16    = (_Float16*)(wsb + (20u << 20));      // 512 KB
    _Float16* AO16    = (_Float16*)(wsb + (16u << 20));      // 8 MB
    _Float16* Wout16  = (_Float16*)(wsb + (31u << 20));      // 256 KB
    float*    cksq    = (float*)(wsb + (32u << 20));         // 256 KB
    float*    rnorm   = (float*)(wsb + (33u << 20));         // 32 KB

    prep_kernel<<<512, 256, 0, stream>>>(fmap, rnorm, fmapT16,
                                         Wq, Wv, gamma, Wout, Wg16, Wout16);
    proj_mfma<<<dim3(64, 16, 2), 256, 0, stream>>>(fmapT16, Wg16, rnorm, Kst, Vst, cksq);
    attn_kernel<<<512, 512, 0, stream>>>(Kst, Vst, cksq, nullkv, AO16);
    outproj_mfma<<<dim3(64, 4, 2), 512, 0, stream>>>(AO16, Wout16, out);
}